// Round 1
// 580.675 us; speedup vs baseline: 1.0065x; 1.0065x over previous
//
#include <hip/hip_runtime.h>
#include <math.h>

// NSLoss: N=16384 pairs, D=128, NUM_SAMPLED=10, weights table 1e6 x 128 f32.
// loss = -(1/N) * sum_i [ log_sigmoid(<emb_i, W[label_i]>)
//                         + sum_k log_sigmoid(-<emb_i, W[negs_ik]>) ]
//
// R2: float4 lanes / two-pairs-per-wave.
//  - lane holds float4 (16B); 32 lanes cover one 512B row; the two 32-lane
//    halves of a wave process two adjacent pairs concurrently.
//  - butterfly is 5 levels (within-half) instead of 6; gather instruction
//    count per pair halves (each load instr moves 1KB/wave, still 512B/row).
//  - 8192 waves (2048 blocks x 4 waves), 11 row-gathers per half issued up
//    front for MLP; partials[2048] + tiny second-kernel reduce (no atomics).
// Algorithmic traffic unchanged: ~101 MB read, 8KB+4B written.

#define NPAIRS 16384
#define DIM 128
#define NSAMP 10
#define PAIRS_PER_BLOCK 8                  // 4 waves x 2 pairs
#define NBLOCKS (NPAIRS / PAIRS_PER_BLOCK) // 2048

__device__ __forceinline__ float log_sigmoid(float x) {
    // stable: min(x,0) - log1p(exp(-|x|))
    return fminf(x, 0.0f) - log1pf(__expf(-fabsf(x)));
}

__global__ __launch_bounds__(256) void nsloss_partial_kernel(
    const float* __restrict__ emb,      // [N, 128]
    const float* __restrict__ weights,  // [1e6, 128]
    const int*   __restrict__ label,    // [N]   (int32 on device: jax x64 off)
    const int*   __restrict__ negs,     // [N, 10]
    float* __restrict__ partials)       // [NBLOCKS]
{
    const int wave = threadIdx.x >> 6;        // 0..3
    const int lane = threadIdx.x & 63;
    const int half = lane >> 5;               // 0 -> pair 2w, 1 -> pair 2w+1
    const int l5   = lane & 31;
    const int pair = blockIdx.x * PAIRS_PER_BLOCK + (wave << 1) + half;

    // emb fragment: half h, lane l5 -> elements [4*l5, 4*l5+3] of row `pair`.
    // Two adjacent rows per wave -> one 1KB fully-coalesced load instr.
    const float4 e = *(const float4*)(emb + (size_t)pair * DIM + 4 * l5);

    // 11 row indices for this half's pair (broadcast within the 32-lane half)
    int idx[NSAMP + 1];
    idx[0] = label[pair];
#pragma unroll
    for (int k = 0; k < NSAMP; ++k) idx[k + 1] = negs[pair * NSAMP + k];

    // issue all 11 row gathers before any reduction (max loads in flight)
    float4 w[NSAMP + 1];
#pragma unroll
    for (int k = 0; k < NSAMP + 1; ++k)
        w[k] = *(const float4*)(weights + ((size_t)idx[k] << 7) + 4 * l5);

    float loss = 0.0f;
#pragma unroll
    for (int k = 0; k < NSAMP + 1; ++k) {
        float s = e.x * w[k].x + e.y * w[k].y + e.z * w[k].z + e.w * w[k].w;
        // 5-level butterfly: xor masks <32 stay inside each 32-lane half
#pragma unroll
        for (int off = 16; off >= 1; off >>= 1)
            s += __shfl_xor(s, off, 64);
        loss += log_sigmoid(k == 0 ? s : -s);
    }
    // combine the two pairs of this wave
    loss += __shfl_xor(loss, 32, 64);

    __shared__ float part[4];
    if (lane == 0) part[wave] = loss;
    __syncthreads();
    if (threadIdx.x == 0)
        partials[blockIdx.x] = (part[0] + part[1]) + (part[2] + part[3]);
}

__global__ __launch_bounds__(256) void nsloss_reduce_kernel(
    const float* __restrict__ partials,  // [NBLOCKS]
    float* __restrict__ out)             // [1]
{
    const int t = threadIdx.x;
    float s = 0.0f;
#pragma unroll
    for (int j = 0; j < NBLOCKS / 256; ++j)   // 8 coalesced passes
        s += partials[j * 256 + t];
#pragma unroll
    for (int off = 32; off >= 1; off >>= 1)
        s += __shfl_xor(s, off, 64);

    __shared__ float part[4];
    if ((t & 63) == 0) part[t >> 6] = s;
    __syncthreads();
    if (t == 0)
        out[0] = ((part[0] + part[1]) + (part[2] + part[3])) * (-1.0f / (float)NPAIRS);
}

extern "C" void kernel_launch(void* const* d_in, const int* in_sizes, int n_in,
                              void* d_out, int out_size, void* d_ws, size_t ws_size,
                              hipStream_t stream) {
    // inputs (setup_inputs order): y_hat[N] (unused), emb[N*128], weights[1e6*128],
    // label[N] (int32), negs[N*10] (int32)
    const float* emb     = (const float*)d_in[1];
    const float* weights = (const float*)d_in[2];
    const int*   label   = (const int*)d_in[3];
    const int*   negs    = (const int*)d_in[4];
    float* out      = (float*)d_out;
    float* partials = (float*)d_ws;   // 2048 floats, fully overwritten each launch

    nsloss_partial_kernel<<<NBLOCKS, 256, 0, stream>>>(emb, weights, label, negs, partials);
    nsloss_reduce_kernel<<<1, 256, 0, stream>>>(partials, out);
}